// Round 5
// baseline (237.339 us; speedup 1.0000x reference)
//
#include <hip/hip_runtime.h>
#include <hip/hip_bf16.h>
#include <hip/hip_fp16.h>

#define NT 4096
#define NE 131072

// ws layout (bytes)
#define OFF_DEG  0            // float[4096]
#define OFF_A    16384        // bf16[4096*4096] = 32 MiB (dead after K3)
#define OFF_G1T  33570816     // bf16[16][4096]  (dead after K1)
#define OFF_G2T  33701888     // bf16[32][4096]  (dead after K2)
#define OFF_G3T  33964032     // bf16[32][4096]  (dead after K3)
#define OFF_C    16384        // f16[16*32*256*256] = 64 MiB, overlaps A/G1/G2/G3
#define OFF_H3   67125248     // bf16[4096][32]
#define OFF_W2T  67387392     // uint[1568]
// total ~64.3 MB

typedef __attribute__((ext_vector_type(8))) short bf16x8;
typedef __attribute__((ext_vector_type(4))) float f32x4;

__device__ inline unsigned int align16(unsigned int hi, unsigned int lo) {
#if __has_builtin(__builtin_amdgcn_alignbit)
    return __builtin_amdgcn_alignbit(hi, lo, 16);
#else
    return (lo >> 16) | (hi << 16);
#endif
}

__device__ inline unsigned short bfb(float x) {
    return __hip_bfloat16_raw(__float2bfloat16(x)).x;
}

__device__ inline void atomic_add_bf16(unsigned short* base, unsigned int idx, float v) {
    unsigned long long addr = (unsigned long long)(base + (idx & ~1u));
    unsigned int bits = ((unsigned int)bfb(v)) << ((idx & 1u) * 16);
    asm volatile("global_atomic_pk_add_bf16 %0, %1, off" :: "v"(addr), "v"(bits) : "memory");
}

// ---------------- setup ----------------

__global__ void k_deg(const int* __restrict__ ei, const float* __restrict__ ew,
                      float* __restrict__ deg) {
    int e = blockIdx.x * 256 + threadIdx.x;
    if (e < NE) atomicAdd(&deg[ei[NE + e]], ew[e]);
}

// scatter edges into dense bf16 A[dst][src] + diagonal + G1^T = (x@W0)^T + conv weight pack
__global__ void k_scatter(const int* __restrict__ ei, const float* __restrict__ ew,
                          const float* __restrict__ deg, unsigned short* __restrict__ A16,
                          const float* __restrict__ x, const float* __restrict__ W0,
                          unsigned short* __restrict__ G1T,
                          const float* __restrict__ Wp, unsigned int* __restrict__ w2) {
    int e = blockIdx.x * 256 + threadIdx.x;
    if (e < NE) {
        int s = ei[e], d = ei[NE + e];
        float v = rsqrtf(deg[s] + 2.f) * ew[e] * rsqrtf(deg[d] + 2.f);
        atomic_add_bf16(A16, (unsigned int)d * 4096u + (unsigned int)s, v);
    }
    if (e < NT) {
        atomic_add_bf16(A16, (unsigned int)e * 4097u, 2.f / (deg[e] + 2.f));
    }
    if (e < NT * 16) {
        int node = e & 4095, co = e >> 12;       // co wave-uniform
        const float4* xr = (const float4*)(x + node * 32);
        float a = 0.f;
        #pragma unroll
        for (int r = 0; r < 8; r++) {
            float4 f = xr[r];
            a += f.x * W0[(r*4+0)*16 + co] + f.y * W0[(r*4+1)*16 + co]
               + f.z * W0[(r*4+2)*16 + co] + f.w * W0[(r*4+3)*16 + co];
        }
        G1T[co * 4096 + node] = bfb(a);
    }
    if (e >= NE - 1568) {
        int k = e - (NE - 1568);
        __half hh = __float2half(Wp[k]);
        __half2 h2 = __halves2half2(hh, hh);
        w2[k] = *(unsigned int*)&h2;
    }
}

// ---------------- GCN layer: out = relu(A @ G + b) [@ Wnext] ----------------
// 256 blocks (16 dst rows each) x 512 threads (8 waves). Wave w covers k in [w*512,(w+1)*512).
// Gt is [NIN][4096] bf16 (transposed). Output: LAST ? h3[node][32] : Gout^T[NOUT][4096].

template <int NIN, int NOUT, bool LAST>
__global__ __launch_bounds__(512) void k_gcn(const unsigned short* __restrict__ A16,
                                             const unsigned short* __restrict__ Gt,
                                             const float* __restrict__ bias,
                                             const float* __restrict__ W,
                                             unsigned short* __restrict__ Gout) {
    constexpr int T = NIN / 16;
    __shared__ float red[8][T][16][16];
    __shared__ unsigned short wtile[16 * 40];
    int mt = blockIdx.x;
    int tid = threadIdx.x;
    int w = tid >> 6, lane = tid & 63, m = lane & 15, q = lane >> 4;
    int kw = w * 512;

    const unsigned short* arow = A16 + (size_t)(mt * 16 + m) * 4096 + kw + q * 8;
    f32x4 acc[T];
    #pragma unroll
    for (int t = 0; t < T; t++) acc[t] = (f32x4){0.f, 0.f, 0.f, 0.f};

    // epilogue W-frag (B operand = W^T rows): lane: cn = w*16+m, ci = q*8+j
    bf16x8 wfrag;
    if (!LAST && w < NOUT / 16) {
        #pragma unroll
        for (int j = 0; j < 8; j++) {
            int ci = q * 8 + j;
            wfrag[j] = (ci < NIN) ? (short)bfb(W[ci * NOUT + w * 16 + m]) : (short)0;
        }
    }

    #pragma unroll 4
    for (int s = 0; s < 16; s++) {
        bf16x8 bA = *(const bf16x8*)(arow + s * 32);
        #pragma unroll
        for (int t = 0; t < T; t++) {
            bf16x8 af = *(const bf16x8*)(Gt + (size_t)(t * 16 + m) * 4096 + kw + q * 8 + s * 32);
            acc[t] = __builtin_amdgcn_mfma_f32_16x16x32_bf16(af, bA, acc[t], 0, 0, 0);
        }
    }
    // acc[t]: lane col (m) = dst-within-tile, rows q*4+r = co-within-tile
    #pragma unroll
    for (int t = 0; t < T; t++)
        #pragma unroll
        for (int r = 0; r < 4; r++) red[w][t][q*4 + r][m] = acc[t][r];
    __syncthreads();

    if (tid < T * 256) {
        int dstp = tid & 15, cop = (tid >> 4) & 15, t = tid >> 8;
        float sum = 0.f;
        #pragma unroll
        for (int w8 = 0; w8 < 8; w8++) sum += red[w8][t][cop][dstp];
        int co = t * 16 + cop;
        float val = fmaxf(sum + bias[co], 0.f);
        if (LAST) Gout[(size_t)(mt * 16 + dstp) * 32 + co] = bfb(val);
        else      wtile[dstp * 40 + co] = bfb(val);
    }
    if (!LAST && NIN == 16 && tid >= 256 && tid < 512) {
        int idx = tid - 256;
        wtile[(idx & 15) * 40 + 16 + ((idx >> 4) & 15)] = 0;
    }
    __syncthreads();

    if (!LAST && w < NOUT / 16) {
        bf16x8 af = *(const bf16x8*)&wtile[m * 40 + q * 8];   // rows=node, k=ci
        f32x4 o = (f32x4){0.f, 0.f, 0.f, 0.f};
        o = __builtin_amdgcn_mfma_f32_16x16x32_bf16(af, wfrag, o, 0, 0, 0);
        // lane col = cn-within-16, rows q*4+r = node-within-16
        uint2 ov;
        ov.x = (unsigned int)bfb(o[0]) | ((unsigned int)bfb(o[1]) << 16);
        ov.y = (unsigned int)bfb(o[2]) | ((unsigned int)bfb(o[3]) << 16);
        *(uint2*)&Gout[(size_t)(w * 16 + m) * 4096 + mt * 16 + q * 4] = ov;
    }
}

// ---------------- C1 via MFMA: per (b,h), C = (Z diag(w_h)) Z^T, 256x256x32 ----------------

__global__ __launch_bounds__(256) void k_c1(const unsigned short* __restrict__ h3,
                                            const float* __restrict__ Wc,
                                            const float* __restrict__ bc,
                                            unsigned short* __restrict__ c) {
    __shared__ unsigned short zb[256 * 40];
    __shared__ unsigned short zwb[256 * 40];
    int blk = blockIdx.x;
    int b = blk >> 5, h = blk & 31;
    int tid = threadIdx.x;
    int lane = tid & 63, w = tid >> 6;
    int m = lane & 15, q = lane >> 4;

    {
        const uint4* zp = (const uint4*)(h3 + (size_t)(b * 256 + tid) * 32);
        unsigned int zr[16];
        #pragma unroll
        for (int k = 0; k < 4; k++) ((uint4*)zr)[k] = zp[k];
        unsigned int uw[16];
        #pragma unroll
        for (int k = 0; k < 16; k++) {
            float lo = __uint_as_float(zr[k] << 16);
            float hi = __uint_as_float(zr[k] & 0xffff0000u);
            float wl = Wc[h * 32 + 2 * k];
            float wh = Wc[h * 32 + 2 * k + 1];
            uw[k] = (unsigned int)bfb(lo * wl) | ((unsigned int)bfb(hi * wh) << 16);
        }
        uint4* zbp = (uint4*)&zb[tid * 40];
        uint4* zwp = (uint4*)&zwb[tid * 40];
        #pragma unroll
        for (int k = 0; k < 4; k++) {
            zbp[k] = ((uint4*)zr)[k];
            zwp[k] = ((uint4*)uw)[k];
        }
    }
    __syncthreads();

    bf16x8 bt[16];
    #pragma unroll
    for (int nt = 0; nt < 16; nt++)
        bt[nt] = *(const bf16x8*)&zb[(nt * 16 + m) * 40 + q * 8];

    bf16x8 af[4];
    #pragma unroll
    for (int s = 0; s < 4; s++)
        af[s] = *(const bf16x8*)&zwb[((w * 4 + s) * 16 + m) * 40 + q * 8];

    float bch = bc[h];
    size_t plane = ((size_t)blk) << 16;

    #pragma unroll
    for (int s = 0; s < 4; s++) {
        f32x4 acc[16];
        #pragma unroll
        for (int nt = 0; nt < 16; nt++) {
            acc[nt] = (f32x4){0.f, 0.f, 0.f, 0.f};
            acc[nt] = __builtin_amdgcn_mfma_f32_16x16x32_bf16(af[s], bt[nt], acc[nt], 0, 0, 0);
        }
        int jbase = (w * 4 + s) * 16 + q * 4;
        #pragma unroll
        for (int nt = 0; nt < 16; nt++) {
            float v0 = fmaxf(acc[nt][0] + bch, 0.f);
            float v1 = fmaxf(acc[nt][1] + bch, 0.f);
            float v2 = fmaxf(acc[nt][2] + bch, 0.f);
            float v3 = fmaxf(acc[nt][3] + bch, 0.f);
            __half2 p0 = __floats2half2_rn(v0, v1);
            __half2 p1 = __floats2half2_rn(v2, v3);
            uint2 o;
            o.x = *(unsigned int*)&p0;
            o.y = *(unsigned int*)&p1;
            *(uint2*)&c[plane + (size_t)(nt * 16 + m) * 256 + jbase] = o;
        }
    }
}

// ---------------- C2: 7x7 conv (32ch->1) + bias + sigmoid ----------------
// 256 blocks: tile 64j x 64i. 256 thr: tx=tid&15 (4 px), ty=tid>>4 (4 rows).
// LDS rows 70 x stride 38 dw, double-buffered; b64 reads.

__global__ __launch_bounds__(256) void k_conv(const __half* __restrict__ c,
                                              const unsigned int* __restrict__ w2,
                                              const float* __restrict__ bp,
                                              float* __restrict__ out) {
    __shared__ __align__(16) unsigned int tile[2][70 * 38];
    int b = blockIdx.z, i0 = blockIdx.y * 64, j0 = blockIdx.x * 64;
    int tid = threadIdx.x;
    int tx = tid & 15, ty = tid >> 4;

    int goff[11]; int loff[11]; bool gok[11]; bool sok[11];
    #pragma unroll
    for (int k = 0; k < 11; k++) {
        int idx = tid + k * 256;
        sok[k] = idx < 2590;                  // 70*37
        int r = idx / 37, cc = idx - r * 37;
        int gi = i0 - 3 + r;
        int gdw = (j0 >> 1) - 2 + cc;
        gok[k] = sok[k] && gi >= 0 && gi < 256 && gdw >= 0 && gdw < 128;
        goff[k] = gok[k] ? (gi * 128 + gdw) : 0;
        loff[k] = r * 38 + cc;
    }

    const unsigned int* cgd = (const unsigned int*)c;
    {
        const unsigned int* cp = cgd + ((size_t)(b * 32) << 15);
        #pragma unroll
        for (int k = 0; k < 11; k++) {
            unsigned int v = gok[k] ? cp[goff[k]] : 0u;
            if (sok[k]) tile[0][loff[k]] = v;
        }
    }
    __syncthreads();

    __half2 acc[4][2];
    __half2 z2 = __float2half2_rn(0.f);
    #pragma unroll
    for (int o = 0; o < 4; o++) { acc[o][0] = z2; acc[o][1] = z2; }

    for (int h = 0; h < 32; h++) {
        unsigned int sv[11];
        if (h < 31) {
            const unsigned int* cp = cgd + ((size_t)(b * 32 + h + 1) << 15);
            #pragma unroll
            for (int k = 0; k < 11; k++) sv[k] = gok[k] ? cp[goff[k]] : 0u;
        }

        const unsigned int* T = &tile[h & 1][0];
        const __half2* wrow = (const __half2*)w2 + h * 49;
        #pragma unroll
        for (int r8 = 0; r8 < 10; r8++) {
            const unsigned int* rp = T + (ty * 4 + r8) * 38 + tx * 2;
            uint2 ea = *(const uint2*)rp;
            uint2 eb = *(const uint2*)(rp + 2);
            uint2 ec = *(const uint2*)(rp + 4);
            unsigned int E[6] = {ea.x, ea.y, eb.x, eb.y, ec.x, ec.y};
            unsigned int O[5];
            #pragma unroll
            for (int k = 0; k < 5; k++) O[k] = align16(E[k + 1], E[k]);
            #pragma unroll
            for (int o = 0; o < 4; o++) {
                int di = r8 - o;
                if (di < 0 || di > 6) continue;
                #pragma unroll
                for (int dj = 0; dj < 7; dj++) {
                    __half2 wv = wrow[di * 7 + dj];
                    int d = dj - 3;
                    unsigned int p0 = (d & 1) ? O[(d + 3) >> 1] : E[(d + 4) >> 1];
                    unsigned int p1 = (d & 1) ? O[((d + 3) >> 1) + 1] : E[((d + 4) >> 1) + 1];
                    acc[o][0] = __hfma2(wv, *(__half2*)&p0, acc[o][0]);
                    acc[o][1] = __hfma2(wv, *(__half2*)&p1, acc[o][1]);
                }
            }
        }

        if (h < 31) {
            unsigned int* Tn = &tile[(h + 1) & 1][0];
            #pragma unroll
            for (int k = 0; k < 11; k++) if (sok[k]) Tn[loff[k]] = sv[k];
        }
        __syncthreads();
    }

    float bpv = bp[0];
    #pragma unroll
    for (int o = 0; o < 4; o++) {
        float2 f0 = __half22float2(acc[o][0]);
        float2 f1 = __half22float2(acc[o][1]);
        float4 r;
        r.x = 1.0f / (1.0f + __expf(-(f0.x + bpv)));
        r.y = 1.0f / (1.0f + __expf(-(f0.y + bpv)));
        r.z = 1.0f / (1.0f + __expf(-(f1.x + bpv)));
        r.w = 1.0f / (1.0f + __expf(-(f1.y + bpv)));
        *(float4*)&out[((size_t)(b * 256 + i0 + ty * 4 + o)) * 256 + j0 + tx * 4] = r;
    }
}

// ---------------- launch ----------------

extern "C" void kernel_launch(void* const* d_in, const int* in_sizes, int n_in,
                              void* d_out, int out_size, void* d_ws, size_t ws_size,
                              hipStream_t stream) {
    const float* x  = (const float*)d_in[0];
    const int*   ei = (const int*)d_in[1];
    const float* ew = (const float*)d_in[2];
    const float* W0 = (const float*)d_in[4];
    const float* b0 = (const float*)d_in[5];
    const float* W1 = (const float*)d_in[6];
    const float* b1 = (const float*)d_in[7];
    const float* W2 = (const float*)d_in[8];
    const float* b2 = (const float*)d_in[9];
    const float* Wc = (const float*)d_in[10];
    const float* bc = (const float*)d_in[11];
    const float* Wp = (const float*)d_in[12];
    const float* bp = (const float*)d_in[13];

    char* ws = (char*)d_ws;
    float*          deg  = (float*)(ws + OFF_DEG);
    unsigned short* A16  = (unsigned short*)(ws + OFF_A);
    unsigned short* G1T  = (unsigned short*)(ws + OFF_G1T);
    unsigned short* G2T  = (unsigned short*)(ws + OFF_G2T);
    unsigned short* G3T  = (unsigned short*)(ws + OFF_G3T);
    unsigned short* H3   = (unsigned short*)(ws + OFF_H3);
    unsigned int*   w2t  = (unsigned int*)(ws + OFF_W2T);
    unsigned short* cbuf = (unsigned short*)(ws + OFF_C);

    (void)hipMemsetAsync(d_ws, 0, 16384 + 33554432, stream);   // deg + A16

    k_deg    <<<NE/256, 256, 0, stream>>>(ei, ew, deg);
    k_scatter<<<NE/256, 256, 0, stream>>>(ei, ew, deg, A16, x, W0, G1T, Wp, w2t);

    k_gcn<16, 32, false><<<256, 512, 0, stream>>>(A16, G1T, b0, W1, G2T);
    k_gcn<32, 32, false><<<256, 512, 0, stream>>>(A16, G2T, b1, W2, G3T);
    k_gcn<32, 32, true> <<<256, 512, 0, stream>>>(A16, G3T, b2, nullptr, H3);

    k_c1  <<<512, 256, 0, stream>>>(H3, Wc, bc, cbuf);
    k_conv<<<dim3(4,4,16), 256, 0, stream>>>((const __half*)cbuf, w2t, bp, (float*)d_out);
}

// Round 6
// 196.473 us; speedup vs baseline: 1.2080x; 1.2080x over previous
//
#include <hip/hip_runtime.h>
#include <hip/hip_bf16.h>
#include <hip/hip_fp16.h>

#define NT 4096
#define NE 131072

// ws layout (bytes)
#define OFF_DEG  0            // float[4096]
#define OFF_A    16384        // bf16[4096*4096] = 32 MiB
#define OFF_G1T  33570816     // bf16[16][4096]
#define OFF_G2T  33701888     // bf16[32][4096]
#define OFF_G3T  33964032     // bf16[32][4096]
#define OFF_H3   34226176     // bf16[4096][32]
#define OFF_W2T  34488320     // uint[1568]
// total ~34.5 MB

typedef __attribute__((ext_vector_type(8))) short bf16x8;
typedef __attribute__((ext_vector_type(4))) float f32x4;

__device__ inline unsigned int align16(unsigned int hi, unsigned int lo) {
#if __has_builtin(__builtin_amdgcn_alignbit)
    return __builtin_amdgcn_alignbit(hi, lo, 16);
#else
    return (lo >> 16) | (hi << 16);
#endif
}

__device__ inline unsigned short bfb(float x) {
    return __hip_bfloat16_raw(__float2bfloat16(x)).x;
}

__device__ inline void atomic_add_bf16(unsigned short* base, unsigned int idx, float v) {
    unsigned long long addr = (unsigned long long)(base + (idx & ~1u));
    unsigned int bits = ((unsigned int)bfb(v)) << ((idx & 1u) * 16);
    asm volatile("global_atomic_pk_add_bf16 %0, %1, off" :: "v"(addr), "v"(bits) : "memory");
}

// ---------------- setup ----------------

__global__ void k_deg(const int* __restrict__ ei, const float* __restrict__ ew,
                      float* __restrict__ deg) {
    int e = blockIdx.x * 256 + threadIdx.x;
    if (e < NE) atomicAdd(&deg[ei[NE + e]], ew[e]);
}

__global__ void k_scatter(const int* __restrict__ ei, const float* __restrict__ ew,
                          const float* __restrict__ deg, unsigned short* __restrict__ A16,
                          const float* __restrict__ x, const float* __restrict__ W0,
                          unsigned short* __restrict__ G1T,
                          const float* __restrict__ Wp, unsigned int* __restrict__ w2) {
    int e = blockIdx.x * 256 + threadIdx.x;
    if (e < NE) {
        int s = ei[e], d = ei[NE + e];
        float v = rsqrtf(deg[s] + 2.f) * ew[e] * rsqrtf(deg[d] + 2.f);
        atomic_add_bf16(A16, (unsigned int)d * 4096u + (unsigned int)s, v);
    }
    if (e < NT) {
        atomic_add_bf16(A16, (unsigned int)e * 4097u, 2.f / (deg[e] + 2.f));
    }
    if (e < NT * 16) {
        int node = e & 4095, co = e >> 12;
        const float4* xr = (const float4*)(x + node * 32);
        float a = 0.f;
        #pragma unroll
        for (int r = 0; r < 8; r++) {
            float4 f = xr[r];
            a += f.x * W0[(r*4+0)*16 + co] + f.y * W0[(r*4+1)*16 + co]
               + f.z * W0[(r*4+2)*16 + co] + f.w * W0[(r*4+3)*16 + co];
        }
        G1T[co * 4096 + node] = bfb(a);
    }
    if (e >= NE - 1568) {
        int k = e - (NE - 1568);
        __half hh = __float2half(Wp[k]);
        __half2 h2 = __halves2half2(hh, hh);
        w2[k] = *(unsigned int*)&h2;
    }
}

// ---------------- GCN layer via dense-A MFMA ----------------

template <int NIN, int NOUT, bool LAST>
__global__ __launch_bounds__(512) void k_gcn(const unsigned short* __restrict__ A16,
                                             const unsigned short* __restrict__ Gt,
                                             const float* __restrict__ bias,
                                             const float* __restrict__ W,
                                             unsigned short* __restrict__ Gout) {
    constexpr int T = NIN / 16;
    __shared__ float red[8][T][16][16];
    __shared__ unsigned short wtile[16 * 40];
    int mt = blockIdx.x;
    int tid = threadIdx.x;
    int w = tid >> 6, lane = tid & 63, m = lane & 15, q = lane >> 4;
    int kw = w * 512;

    const unsigned short* arow = A16 + (size_t)(mt * 16 + m) * 4096 + kw + q * 8;
    f32x4 acc[T];
    #pragma unroll
    for (int t = 0; t < T; t++) acc[t] = (f32x4){0.f, 0.f, 0.f, 0.f};

    bf16x8 wfrag;
    if (!LAST && w < NOUT / 16) {
        #pragma unroll
        for (int j = 0; j < 8; j++) {
            int ci = q * 8 + j;
            wfrag[j] = (ci < NIN) ? (short)bfb(W[ci * NOUT + w * 16 + m]) : (short)0;
        }
    }

    #pragma unroll 4
    for (int s = 0; s < 16; s++) {
        bf16x8 bA = *(const bf16x8*)(arow + s * 32);
        #pragma unroll
        for (int t = 0; t < T; t++) {
            bf16x8 af = *(const bf16x8*)(Gt + (size_t)(t * 16 + m) * 4096 + kw + q * 8 + s * 32);
            acc[t] = __builtin_amdgcn_mfma_f32_16x16x32_bf16(af, bA, acc[t], 0, 0, 0);
        }
    }
    #pragma unroll
    for (int t = 0; t < T; t++)
        #pragma unroll
        for (int r = 0; r < 4; r++) red[w][t][q*4 + r][m] = acc[t][r];
    __syncthreads();

    if (tid < T * 256) {
        int dstp = tid & 15, cop = (tid >> 4) & 15, t = tid >> 8;
        float sum = 0.f;
        #pragma unroll
        for (int w8 = 0; w8 < 8; w8++) sum += red[w8][t][cop][dstp];
        int co = t * 16 + cop;
        float val = fmaxf(sum + bias[co], 0.f);
        if (LAST) Gout[(size_t)(mt * 16 + dstp) * 32 + co] = bfb(val);
        else      wtile[dstp * 40 + co] = bfb(val);
    }
    if (!LAST && NIN == 16 && tid >= 256 && tid < 512) {
        int idx = tid - 256;
        wtile[(idx & 15) * 40 + 16 + ((idx >> 4) & 15)] = 0;
    }
    __syncthreads();

    if (!LAST && w < NOUT / 16) {
        bf16x8 af = *(const bf16x8*)&wtile[m * 40 + q * 8];
        f32x4 o = (f32x4){0.f, 0.f, 0.f, 0.f};
        o = __builtin_amdgcn_mfma_f32_16x16x32_bf16(af, wfrag, o, 0, 0, 0);
        uint2 ov;
        ov.x = (unsigned int)bfb(o[0]) | ((unsigned int)bfb(o[1]) << 16);
        ov.y = (unsigned int)bfb(o[2]) | ((unsigned int)bfb(o[3]) << 16);
        *(uint2*)&Gout[(size_t)(w * 16 + m) * 4096 + mt * 16 + q * 4] = ov;
    }
}

// ---------------- fused C1 + 7x7 conv + sigmoid ----------------
// grid (band 16, b 16); 512 thr (8 waves). Per iter (8): MFMA 4 channels of
// c[h] = relu(Zw_h Z^T + bc) into 4 LDS planes (rows i0-3..i0+28, f16,
// stride 272, col pos = j+4, halos zero); then 4x128-thread conv groups
// (R=4 rows, P=8 px) accumulate their channel into f16 regs. End: 4-way
// reduce + sigmoid + store.

__global__ __launch_bounds__(512) void k_cc(const unsigned short* __restrict__ h3,
                                            const float* __restrict__ Wc,
                                            const float* __restrict__ bc,
                                            const unsigned int* __restrict__ w2,
                                            const float* __restrict__ bp,
                                            float* __restrict__ out) {
    __shared__ unsigned short zs[256 * 40];        // 20480 B
    __shared__ float wcs[32 * 36];                 // 4608 B
    __shared__ __align__(16) unsigned short ct[4 * 32 * 272];  // 69632 B
    __shared__ __align__(16) unsigned short pt[4][4096];       // 32768 B

    int band = blockIdx.x, bb = blockIdx.y;
    int i0 = band * 16;
    int tid = threadIdx.x;
    int lane = tid & 63, w = tid >> 6;
    int m = lane & 15, q = lane >> 4;

    // ---- stage ----
    {
        int row = tid >> 1, half = tid & 1;
        const uint4* src = (const uint4*)(h3 + (size_t)(bb * 256 + row) * 32) + half * 2;
        uint4 v0 = src[0], v1 = src[1];
        uint4* dst = (uint4*)&zs[row * 40 + half * 16];
        dst[0] = v0; dst[1] = v1;
    }
    #pragma unroll
    for (int k = tid; k < 1024; k += 512) wcs[(k >> 5) * 36 + (k & 31)] = Wc[k];
    for (int k = tid; k < 4 * 32 * 136; k += 512) ((unsigned int*)ct)[k] = 0;
    __syncthreads();

    // ---- frags (after barrier) ----
    bf16x8 bt[2];          // B operand: i-rows
    bool wok[2];
    #pragma unroll
    for (int nt = 0; nt < 2; nt++) {
        int r = i0 - 3 + nt * 16 + m;
        wok[nt] = (unsigned)r < 256u;
        r = r < 0 ? 0 : (r > 255 ? 255 : r);
        bt[nt] = *(const bf16x8*)&zs[r * 40 + q * 8];
    }
    float zaf[2][8];       // A base: j-rows, unpacked to f32
    #pragma unroll
    for (int jt2 = 0; jt2 < 2; jt2++) {
        bf16x8 za = *(const bf16x8*)&zs[((w * 2 + jt2) * 16 + m) * 40 + q * 8];
        #pragma unroll
        for (int e = 0; e < 8; e++)
            zaf[jt2][e] = __uint_as_float(((unsigned int)(unsigned short)za[e]) << 16);
    }

    int gg = tid >> 7, tx = tid & 31, ty = (tid >> 5) & 3;
    __half2 acc[4][4];
    __half2 zh = __float2half2_rn(0.f);
    #pragma unroll
    for (int o = 0; o < 4; o++)
        #pragma unroll
        for (int p = 0; p < 4; p++) acc[o][p] = zh;

    for (int it = 0; it < 8; it++) {
        // ---- MFMA phase: channels it*4 .. it*4+3 ----
        #pragma unroll
        for (int g = 0; g < 4; g++) {
            int h = it * 4 + g;
            float wf[8];
            *(float4*)&wf[0] = *(const float4*)&wcs[h * 36 + q * 8];
            *(float4*)&wf[4] = *(const float4*)&wcs[h * 36 + q * 8 + 4];
            float bch = bc[h];
            #pragma unroll
            for (int jt2 = 0; jt2 < 2; jt2++) {
                bf16x8 afv;
                #pragma unroll
                for (int e = 0; e < 8; e++) afv[e] = (short)bfb(zaf[jt2][e] * wf[e]);
                int pos = 4 + (w * 2 + jt2) * 16 + q * 4;   // f16 col in row
                #pragma unroll
                for (int nt = 0; nt < 2; nt++) {
                    f32x4 d = (f32x4){0.f, 0.f, 0.f, 0.f};
                    d = __builtin_amdgcn_mfma_f32_16x16x32_bf16(afv, bt[nt], d, 0, 0, 0);
                    if (wok[nt]) {
                        float v0 = fmaxf(d[0] + bch, 0.f);
                        float v1 = fmaxf(d[1] + bch, 0.f);
                        float v2 = fmaxf(d[2] + bch, 0.f);
                        float v3 = fmaxf(d[3] + bch, 0.f);
                        __half2 h0 = __floats2half2_rn(v0, v1);
                        __half2 h1 = __floats2half2_rn(v2, v3);
                        uint2 o2;
                        o2.x = *(unsigned int*)&h0;
                        o2.y = *(unsigned int*)&h1;
                        *(uint2*)&ct[g * 8704 + (nt * 16 + m) * 272 + pos] = o2;
                    }
                }
            }
        }
        __syncthreads();

        // ---- conv phase: group gg convs channel it*4+gg ----
        {
            const unsigned short* C = ct + gg * 8704;
            const __half2* wrow = (const __half2*)w2 + (it * 4 + gg) * 49;
            #pragma unroll
            for (int dr = 0; dr < 10; dr++) {
                const uint4* p4 = (const uint4*)&C[(ty * 4 + dr) * 272 + tx * 8];
                uint4 ua = p4[0], ub = p4[1];
                unsigned int E[8] = {ua.x, ua.y, ua.z, ua.w, ub.x, ub.y, ub.z, ub.w};
                unsigned int O[7];
                #pragma unroll
                for (int k = 0; k < 7; k++) O[k] = align16(E[k + 1], E[k]);
                #pragma unroll
                for (int o = 0; o < 4; o++) {
                    if (dr - o < 0 || dr - o > 6) continue;  // compile-time
                    int di = dr - o;
                    #pragma unroll
                    for (int dj = 0; dj < 7; dj++) {
                        __half2 wv = wrow[di * 7 + dj];
                        #pragma unroll
                        for (int pr = 0; pr < 4; pr++) {
                            int s = 2 * pr + dj + 1;
                            unsigned int pv = (s & 1) ? O[s >> 1] : E[s >> 1];
                            acc[o][pr] = __hfma2(wv, *(__half2*)&pv, acc[o][pr]);
                        }
                    }
                }
            }
        }
        __syncthreads();
    }

    // ---- write partials, reduce, sigmoid, store ----
    #pragma unroll
    for (int o = 0; o < 4; o++) {
        uint4 v;
        v.x = *(unsigned int*)&acc[o][0];
        v.y = *(unsigned int*)&acc[o][1];
        v.z = *(unsigned int*)&acc[o][2];
        v.w = *(unsigned int*)&acc[o][3];
        *(uint4*)&pt[gg][(ty * 4 + o) * 256 + tx * 8] = v;
    }
    __syncthreads();

    {
        int base = tid * 8;
        float fs[8];
        #pragma unroll
        for (int e = 0; e < 8; e++) fs[e] = 0.f;
        #pragma unroll
        for (int g = 0; g < 4; g++) {
            uint4 v = *(const uint4*)&pt[g][base];
            unsigned int uu[4] = {v.x, v.y, v.z, v.w};
            #pragma unroll
            for (int d = 0; d < 4; d++) {
                float2 f = __half22float2(*(__half2*)&uu[d]);
                fs[2 * d] += f.x; fs[2 * d + 1] += f.y;
            }
        }
        float bpv = bp[0];
        float rs[8];
        #pragma unroll
        for (int e = 0; e < 8; e++) rs[e] = 1.0f / (1.0f + __expf(-(fs[e] + bpv)));
        int row = base >> 8, col = base & 255;
        float* op = &out[((size_t)(bb * 256) + i0 + row) * 256 + col];
        *(float4*)op = make_float4(rs[0], rs[1], rs[2], rs[3]);
        *(float4*)(op + 4) = make_float4(rs[4], rs[5], rs[6], rs[7]);
    }
}

// ---------------- launch ----------------

extern "C" void kernel_launch(void* const* d_in, const int* in_sizes, int n_in,
                              void* d_out, int out_size, void* d_ws, size_t ws_size,
                              hipStream_t stream) {
    const float* x  = (const float*)d_in[0];
    const int*   ei = (const int*)d_in[1];
    const float* ew = (const float*)d_in[2];
    const float* W0 = (const float*)d_in[4];
    const float* b0 = (const float*)d_in[5];
    const float* W1 = (const float*)d_in[6];
    const float* b1 = (const float*)d_in[7];
    const float* W2 = (const float*)d_in[8];
    const float* b2 = (const float*)d_in[9];
    const float* Wc = (const float*)d_in[10];
    const float* bc = (const float*)d_in[11];
    const float* Wp = (const float*)d_in[12];
    const float* bp = (const float*)d_in[13];

    char* ws = (char*)d_ws;
    float*          deg  = (float*)(ws + OFF_DEG);
    unsigned short* A16  = (unsigned short*)(ws + OFF_A);
    unsigned short* G1T  = (unsigned short*)(ws + OFF_G1T);
    unsigned short* G2T  = (unsigned short*)(ws + OFF_G2T);
    unsigned short* G3T  = (unsigned short*)(ws + OFF_G3T);
    unsigned short* H3   = (unsigned short*)(ws + OFF_H3);
    unsigned int*   w2t  = (unsigned int*)(ws + OFF_W2T);

    (void)hipMemsetAsync(d_ws, 0, 16384 + 33554432, stream);   // deg + A16

    k_deg    <<<NE/256, 256, 0, stream>>>(ei, ew, deg);
    k_scatter<<<NE/256, 256, 0, stream>>>(ei, ew, deg, A16, x, W0, G1T, Wp, w2t);

    k_gcn<16, 32, false><<<256, 512, 0, stream>>>(A16, G1T, b0, W1, G2T);
    k_gcn<32, 32, false><<<256, 512, 0, stream>>>(A16, G2T, b1, W2, G3T);
    k_gcn<32, 32, true> <<<256, 512, 0, stream>>>(A16, G3T, b2, nullptr, H3);

    k_cc<<<dim3(16, 16), 512, 0, stream>>>(H3, Wc, bc, w2t, bp, (float*)d_out);
}